// Round 13
// baseline (182.544 us; speedup 1.0000x reference)
//
#include <hip/hip_runtime.h>

#define DIM 512
#define HID 2048
#define NEXP 8

typedef __attribute__((ext_vector_type(8))) short v8s;   // 8 x bf16 bits
typedef __attribute__((ext_vector_type(4))) float v4f;   // MFMA accumulator

__device__ __forceinline__ unsigned short f2bf(float f) {
  union { __bf16 b; unsigned short u; } c;
  c.b = (__bf16)f;
  return c.u;
}

// ---------------- routing prep ----------------
__global__ void route_prep(const int* __restrict__ route, int* __restrict__ meta, int ntok) {
  __shared__ int c[NEXP];
  int t = threadIdx.x;
  if (t < NEXP) c[t] = 0;
  __syncthreads();
  for (int n = t; n < ntok; n += blockDim.x) atomicAdd(&c[route[n]], 1);
  __syncthreads();
  if (t == 0) {
    int acc = 0, pacc = 0;
    for (int e = 0; e < NEXP; ++e) {
      meta[e] = c[e];            // count
      meta[NEXP + e] = acc;      // exact offset
      meta[2 * NEXP + e] = acc;  // cursor for fill_perm
      meta[3 * NEXP + e] = pacc; // 128-padded offset (panel rows)
      acc += c[e];
      pacc += ((c[e] + 127) >> 7) << 7;
    }
  }
}

__global__ void fill_perm(const int* __restrict__ route, int* __restrict__ meta,
                          int* __restrict__ perm, int ntok) {
  int n = blockIdx.x * blockDim.x + threadIdx.x;
  if (n < ntok) {
    int p = atomicAdd(&meta[2 * NEXP + route[n]], 1);
    perm[p] = n;
  }
}

// ---------------- x conversion: gathered bf16 A-panels ----------------
// xp per 64-row tile: [kq 0..63][row 0..63][8k] bf16 = 32768 ushorts.
__global__ __launch_bounds__(256) void x_conv(
    const float* __restrict__ x, const int* __restrict__ meta,
    const int* __restrict__ perm, unsigned short* __restrict__ xp)
{
  const int bid = blockIdx.x;
  const int e = bid & 7;
  const int mt = bid >> 3;
  const int cnt = meta[e];
  const int padded = ((cnt + 127) >> 7) << 7;
  if (mt * 64 >= padded) return;
  const int off  = meta[NEXP + e];
  const int poff = meta[3 * NEXP + e];
  const int t = threadIdx.x;
  const int r = t & 63, q = t >> 6;          // row, quarter (128 floats)
  int arow = mt * 64 + r; if (arow >= cnt) arow = cnt - 1;  // clamp (dup rows)
  const float* src = x + (size_t)perm[off + arow] * DIM + q * 128;
  unsigned short* dst = xp + (size_t)((poff + mt * 64) >> 6) * 32768;
  #pragma unroll
  for (int j = 0; j < 16; ++j) {
    float4 f0 = ((const float4*)src)[2 * j];
    float4 f1 = ((const float4*)src)[2 * j + 1];
    v8s v;
    v[0] = (short)f2bf(f0.x); v[1] = (short)f2bf(f0.y);
    v[2] = (short)f2bf(f0.z); v[3] = (short)f2bf(f0.w);
    v[4] = (short)f2bf(f1.x); v[5] = (short)f2bf(f1.y);
    v[6] = (short)f2bf(f1.z); v[7] = (short)f2bf(f1.w);
    *(v8s*)(dst + (size_t)((q * 16 + j) * 64 + r) * 8) = v;
  }
}

// ---------------- w_out conversion (r10/r12-proven) ----------------
__global__ __launch_bounds__(256) void wo_conv(
    const float* __restrict__ wo, unsigned short* __restrict__ wop)
{
  const int s = blockIdx.x;            // 64-K chunk (32)
  const int j = blockIdx.y;            // n-stripe of 64 (8)
  const int e = blockIdx.z;
  const float* src = wo + (size_t)e * HID * DIM;
  unsigned short* dst = wop + (((size_t)e * 8 + j) * 32 + s) * 4096;
  const int t = threadIdx.x;
  #pragma unroll
  for (int i = 0; i < 2; ++i) {
    const int c = t + 256 * i;         // chunk in [0,512)
    const int kq = c >> 6, n = c & 63;
    const float* srow = src + (size_t)(s * 64 + kq * 8) * DIM + j * 64 + n;
    v8s r;
    #pragma unroll
    for (int q = 0; q < 8; ++q) r[q] = (short)f2bf(srow[(size_t)q * DIM]);
    *(v8s*)(dst + (size_t)c * 8) = r;
  }
}

// ---------------- GEMM1: persistent LDS weights + register A, NO in-loop barriers ----
// Block = (e, 32-col stripe). One-time: wg/wi f32 slice -> LDS slabs
// [kq 0..63][n 0..31][8k] (64 KB), one __syncthreads. Then waves run fully
// independent: wave tile 64m x 32n x both matrices; A-frags loaded per-wave
// straight from xp panels (global->reg, coalesced 256B chunks); W-frags from
// the read-only slab. Zero barriers in the K loop -> in-wave ILP hides latency.
__global__ __launch_bounds__(256, 2) void gemm1r2(
    const unsigned short* __restrict__ xp,
    const float* __restrict__ wg_, const float* __restrict__ bg_,
    const float* __restrict__ wi_, const float* __restrict__ bi_,
    const int* __restrict__ meta,
    unsigned short* __restrict__ hbuf)
{
  const int bid = blockIdx.x;
  const int e = bid >> 6;              // bid%8 = j%8 -> expert spread over XCDs
  const int j = bid & 63;              // 32-col stripe
  const int cnt = meta[e];
  const int poff = meta[3 * NEXP + e];
  const int padded = ((cnt + 127) >> 7) << 7;
  const int n0 = j * 32;

  // G slab 32K @0 | I slab 32K @32768
  __shared__ __align__(16) unsigned char lds[65536];

  const int t = threadIdx.x;
  const int l = t & 63, w = t >> 6;
  const int fr = l & 15, fg = l >> 4;

  // ---- one-time W conversion: f32 [k][n] -> slab [k>>3][n][k&7] (r12-proven) ----
  {
    const int r0 = t >> 1;             // 0..127
    const int h  = t & 1;              // 16-col half
    #pragma unroll
    for (int m = 0; m < 2; ++m) {
      const float* src = (m ? wi_ : wg_) + (size_t)e * DIM * HID + n0 + h * 16;
      unsigned char* slab = lds + m * 32768;
      #pragma unroll
      for (int p = 0; p < 4; ++p) {
        const int r = p * 128 + r0;    // k-row
        const float* row = src + (size_t)r * HID;
        float f[16];
        #pragma unroll
        for (int q = 0; q < 4; ++q) {
          float4 v = ((const float4*)row)[q];
          f[4*q] = v.x; f[4*q+1] = v.y; f[4*q+2] = v.z; f[4*q+3] = v.w;
        }
        unsigned char* dst = slab + ((r >> 3) * 32 + h * 16) * 16 + (r & 7) * 2;
        #pragma unroll
        for (int nn = 0; nn < 16; ++nn)
          *(unsigned short*)(dst + nn * 16) = f2bf(f[nn]);
      }
    }
  }
  __syncthreads();                     // slabs ready; read-only hereafter

  // biases for this wave's two 16-col fragments
  const float bg0 = bg_[(size_t)e * HID + n0 + fr];
  const float bg1 = bg_[(size_t)e * HID + n0 + 16 + fr];
  const float bi0 = bi_[(size_t)e * HID + n0 + fr];
  const float bi1 = bi_[(size_t)e * HID + n0 + 16 + fr];

  const int tile0 = poff >> 6;         // poff is 128-aligned

  for (int m0 = w * 64; m0 < padded; m0 += 256) {   // wave-owned 64-row tiles
    v4f aG[4][2], aI[4][2];
    #pragma unroll
    for (int i = 0; i < 4; ++i)
      #pragma unroll
      for (int q = 0; q < 2; ++q) {
        aG[i][q] = (v4f){0.f, 0.f, 0.f, 0.f};
        aI[i][q] = (v4f){0.f, 0.f, 0.f, 0.f};
      }

    for (int s = 0; s < 16; ++s) {     // K = 512, step 32; NO barrier
      v8s af[4];
      #pragma unroll
      for (int mf = 0; mf < 4; ++mf) {
        const int row = m0 + mf * 16 + fr;
        af[mf] = *(const v8s*)(xp + (size_t)(tile0 + (row >> 6)) * 32768 +
                               ((size_t)(s * 4 + fg) * 64 + (row & 63)) * 8);
      }
      v8s gf[2], inf[2];
      #pragma unroll
      for (int nf = 0; nf < 2; ++nf) {
        gf[nf]  = *(const v8s*)(lds + (((s * 4 + fg) * 32) + nf * 16 + fr) * 16);
        inf[nf] = *(const v8s*)(lds + 32768 + (((s * 4 + fg) * 32) + nf * 16 + fr) * 16);
      }
      #pragma unroll
      for (int mf = 0; mf < 4; ++mf)
        #pragma unroll
        for (int nf = 0; nf < 2; ++nf) {
          aG[mf][nf] = __builtin_amdgcn_mfma_f32_16x16x32_bf16(af[mf], gf[nf],  aG[mf][nf], 0, 0, 0);
          aI[mf][nf] = __builtin_amdgcn_mfma_f32_16x16x32_bf16(af[mf], inf[nf], aI[mf][nf], 0, 0, 0);
        }
    }

    // epilogue: bias + SiLU(gate)*in -> hbuf panels (pad rows deterministic)
    #pragma unroll
    for (int nf = 0; nf < 2; ++nf) {
      const int c = n0 + nf * 16 + fr;
      const float bgv = nf ? bg1 : bg0;
      const float biv = nf ? bi1 : bi0;
      #pragma unroll
      for (int mf = 0; mf < 4; ++mf)
        #pragma unroll
        for (int jj = 0; jj < 4; ++jj) {
          const int grow = poff + m0 + mf * 16 + fg * 4 + jj;
          const float g = aG[mf][nf][jj] + bgv;
          const float v = aI[mf][nf][jj] + biv;
          const float hval = g / (1.f + __expf(-g)) * v;
          hbuf[(size_t)(grow >> 6) * 131072 + ((size_t)(c >> 3) * 64 + (grow & 63)) * 8 + (c & 7)] = f2bf(hval);
        }
    }
  }
}

// ---------------- GEMM2: fully LDS-free register-tile ----------------
// Wave = 32m x 32n output; A-frags from hbuf panels, B-frags from wop panels,
// all global->reg (coalesced 256B chunks). No LDS, no barriers; 64 K-steps
// unrolled x4 for load pipelining. Block = 4 waves stacked in m (128m x 32n).
__global__ __launch_bounds__(256, 8) void gemm2r2(
    const unsigned short* __restrict__ hbuf,
    const unsigned short* __restrict__ wop, const float* __restrict__ bo_,
    const int* __restrict__ meta, const int* __restrict__ perm,
    float* __restrict__ out)
{
  const int bid = blockIdx.x;
  const int stripe = bid & 127;        // e*16 + jn: 128 stripes, %8==0 XCD-spread
  const int mt = bid >> 7;
  const int e = stripe >> 4, jn = stripe & 15;   // jn: 32-col stripe
  const int cnt = meta[e];
  const int m0b = mt * 128;
  if (m0b >= cnt) return;
  const int off = meta[NEXP + e], poff = meta[3 * NEXP + e];
  const int n0 = jn * 32;

  const int t = threadIdx.x;
  const int l = t & 63, w = t >> 6;
  const int fr = l & 15, fg = l >> 4;

  const int m0 = m0b + w * 32;         // wave's 32-row tile (within padded)
  const int tile0 = poff >> 6;

  const unsigned short* pb = wop + ((size_t)e * 8 + (jn >> 1)) * 131072;
  const int nb = (jn & 1) * 32;        // 32-col half within the 64-wide panel

  v4f acc[2][2];
  #pragma unroll
  for (int i = 0; i < 2; ++i) {
    acc[i][0] = (v4f){0.f, 0.f, 0.f, 0.f};
    acc[i][1] = (v4f){0.f, 0.f, 0.f, 0.f};
  }

  // precompute lane row addresses (rows fixed across K)
  const int row0 = m0 + fr;            // mf=0
  const int row1 = m0 + 16 + fr;       // mf=1
  const size_t abase0 = (size_t)(tile0 + (row0 >> 6)) * 131072 + (size_t)(row0 & 63) * 8;
  const size_t abase1 = (size_t)(tile0 + (row1 >> 6)) * 131072 + (size_t)(row1 & 63) * 8;

  #pragma unroll 4
  for (int s = 0; s < 64; ++s) {       // K = 2048, step 32; NO barrier, NO LDS
    const int kq = s * 4 + fg;         // 0..255
    v8s a0 = *(const v8s*)(hbuf + abase0 + (size_t)kq * 512);
    v8s a1 = *(const v8s*)(hbuf + abase1 + (size_t)kq * 512);
    const size_t boff = (size_t)(s >> 1) * 4096 +
                        ((size_t)((s & 1) * 4 + fg) * 64 + nb) * 8;
    v8s b0 = *(const v8s*)(pb + boff + (size_t)fr * 8);
    v8s b1 = *(const v8s*)(pb + boff + (size_t)(16 + fr) * 8);
    acc[0][0] = __builtin_amdgcn_mfma_f32_16x16x32_bf16(a0, b0, acc[0][0], 0, 0, 0);
    acc[0][1] = __builtin_amdgcn_mfma_f32_16x16x32_bf16(a0, b1, acc[0][1], 0, 0, 0);
    acc[1][0] = __builtin_amdgcn_mfma_f32_16x16x32_bf16(a1, b0, acc[1][0], 0, 0, 0);
    acc[1][1] = __builtin_amdgcn_mfma_f32_16x16x32_bf16(a1, b1, acc[1][1], 0, 0, 0);
  }

  #pragma unroll
  for (int nf = 0; nf < 2; ++nf) {
    const int c = n0 + nf * 16 + fr;
    const float bo = bo_[(size_t)e * DIM + c];
    #pragma unroll
    for (int mf = 0; mf < 2; ++mf)
      #pragma unroll
      for (int jj = 0; jj < 4; ++jj) {
        const int r = m0 + mf * 16 + fg * 4 + jj;   // expert-local row
        if (r < cnt)
          out[(size_t)perm[off + r] * DIM + c] = acc[mf][nf][jj] + bo;
      }
  }
}

// ---------------- launch ----------------
extern "C" void kernel_launch(void* const* d_in, const int* in_sizes, int n_in,
                              void* d_out, int out_size, void* d_ws, size_t ws_size,
                              hipStream_t stream) {
  const float* x      = (const float*)d_in[0];
  const int*   route  = (const int*)d_in[1];
  const float* w_in   = (const float*)d_in[2];
  const float* b_in   = (const float*)d_in[3];
  const float* w_gate = (const float*)d_in[4];
  const float* b_gate = (const float*)d_in[5];
  const float* w_out  = (const float*)d_in[6];
  const float* b_out  = (const float*)d_in[7];
  float* out = (float*)d_out;

  const int ntok = in_sizes[1];  // 4096

  int* meta = (int*)d_ws;
  int* perm = (int*)((char*)d_ws + 128);

  // ws: meta/perm 64K | xp 5.25MB | wop 16MB | hbuf 21MB  (~43 MB total)
  unsigned short* xp   = (unsigned short*)((char*)d_ws + 65536);
  unsigned short* wop  = (unsigned short*)((char*)d_ws + 65536 + 5242880);
  unsigned short* hbuf = (unsigned short*)((char*)d_ws + 65536 + 5242880 + 16777216);

  const int MT64  = (ntok + 63) / 64;
  const int MT128 = (ntok + 127) / 128;

  route_prep<<<1, 256, 0, stream>>>(route, meta, ntok);
  fill_perm<<<(ntok + 255) / 256, 256, 0, stream>>>(route, meta, perm, ntok);
  x_conv<<<NEXP * MT64, 256, 0, stream>>>(x, meta, perm, xp);
  gemm1r2<<<NEXP * 64, 256, 0, stream>>>(
      xp, w_gate, b_gate, w_in, b_in, meta, hbuf);
  wo_conv<<<dim3(32, 8, 8), 256, 0, stream>>>(w_out, wop);
  gemm2r2<<<128 * MT128, 256, 0, stream>>>(
      hbuf, wop, b_out, meta, perm, out);
}

// Round 14
// 113.774 us; speedup vs baseline: 1.6044x; 1.6044x over previous
//
#include <hip/hip_runtime.h>

#define DIM 512
#define HID 2048
#define NEXP 8

typedef __attribute__((ext_vector_type(8))) short v8s;   // 8 x bf16 bits
typedef __attribute__((ext_vector_type(4))) float v4f;   // MFMA accumulator

__device__ __forceinline__ unsigned short f2bf(float f) {
  union { __bf16 b; unsigned short u; } c;
  c.b = (__bf16)f;
  return c.u;
}

__device__ __forceinline__ void gload16(const void* g, void* l) {
  __builtin_amdgcn_global_load_lds(
      (const __attribute__((address_space(1))) unsigned int*)g,
      (__attribute__((address_space(3))) unsigned int*)l, 16, 0, 0);
}

// ---------------- routing prep ----------------
__global__ void route_prep(const int* __restrict__ route, int* __restrict__ meta, int ntok) {
  __shared__ int c[NEXP];
  int t = threadIdx.x;
  if (t < NEXP) c[t] = 0;
  __syncthreads();
  for (int n = t; n < ntok; n += blockDim.x) atomicAdd(&c[route[n]], 1);
  __syncthreads();
  if (t == 0) {
    int acc = 0, pacc = 0;
    for (int e = 0; e < NEXP; ++e) {
      meta[e] = c[e];            // count
      meta[NEXP + e] = acc;      // exact offset
      meta[2 * NEXP + e] = acc;  // cursor for fill_perm
      meta[3 * NEXP + e] = pacc; // 128-padded offset (panel rows)
      acc += c[e];
      pacc += ((c[e] + 127) >> 7) << 7;
    }
  }
}

__global__ void fill_perm(const int* __restrict__ route, int* __restrict__ meta,
                          int* __restrict__ perm, int ntok) {
  int n = blockIdx.x * blockDim.x + threadIdx.x;
  if (n < ntok) {
    int p = atomicAdd(&meta[2 * NEXP + route[n]], 1);
    perm[p] = n;
  }
}

// ---------------- x conversion: gathered bf16 A-panels ----------------
// xp per 64-row tile: [kq 0..63][row 0..63][8k] bf16 = 32768 ushorts.
__global__ __launch_bounds__(256) void x_conv(
    const float* __restrict__ x, const int* __restrict__ meta,
    const int* __restrict__ perm, unsigned short* __restrict__ xp)
{
  const int bid = blockIdx.x;
  const int e = bid & 7;
  const int mt = bid >> 3;
  const int cnt = meta[e];
  const int padded = ((cnt + 127) >> 7) << 7;
  if (mt * 64 >= padded) return;
  const int off  = meta[NEXP + e];
  const int poff = meta[3 * NEXP + e];
  const int t = threadIdx.x;
  const int r = t & 63, q = t >> 6;          // row, quarter (128 floats)
  int arow = mt * 64 + r; if (arow >= cnt) arow = cnt - 1;  // clamp (dup rows)
  const float* src = x + (size_t)perm[off + arow] * DIM + q * 128;
  unsigned short* dst = xp + (size_t)((poff + mt * 64) >> 6) * 32768;
  #pragma unroll
  for (int j = 0; j < 16; ++j) {
    float4 f0 = ((const float4*)src)[2 * j];
    float4 f1 = ((const float4*)src)[2 * j + 1];
    v8s v;
    v[0] = (short)f2bf(f0.x); v[1] = (short)f2bf(f0.y);
    v[2] = (short)f2bf(f0.z); v[3] = (short)f2bf(f0.w);
    v[4] = (short)f2bf(f1.x); v[5] = (short)f2bf(f1.y);
    v[6] = (short)f2bf(f1.z); v[7] = (short)f2bf(f1.w);
    *(v8s*)(dst + (size_t)((q * 16 + j) * 64 + r) * 8) = v;
  }
}

// ---------------- w_out conversion (r10/r12-proven) ----------------
__global__ __launch_bounds__(256) void wo_conv(
    const float* __restrict__ wo, unsigned short* __restrict__ wop)
{
  const int s = blockIdx.x;            // 64-K chunk (32)
  const int j = blockIdx.y;            // n-stripe of 64 (8)
  const int e = blockIdx.z;
  const float* src = wo + (size_t)e * HID * DIM;
  unsigned short* dst = wop + (((size_t)e * 8 + j) * 32 + s) * 4096;
  const int t = threadIdx.x;
  #pragma unroll
  for (int i = 0; i < 2; ++i) {
    const int c = t + 256 * i;         // chunk in [0,512)
    const int kq = c >> 6, n = c & 63;
    const float* srow = src + (size_t)(s * 64 + kq * 8) * DIM + j * 64 + n;
    v8s r;
    #pragma unroll
    for (int q = 0; q < 8; ++q) r[q] = (short)f2bf(srow[(size_t)q * DIM]);
    *(v8s*)(dst + (size_t)c * 8) = r;
  }
}

// ---------------- GEMM1: persistent LDS weights + register A, barrier-free ----------
// Block = (e, 32-col stripe). One-time: wg/wi f32 slice -> LDS slabs
// [kq 0..63][n 0..31][8k] (64 KB), one __syncthreads. Then waves free-run:
// wave tile 32m x 32n x both matrices (acc = 32 VGPR, no spill); A-frags
// global->reg from xp panels (L2-resident), W-frags from read-only slab.
// Zero in-loop barriers; unroll-2 for load ILP. 2 blocks/CU.
__global__ __launch_bounds__(256, 2) void gemm1f2(
    const unsigned short* __restrict__ xp,
    const float* __restrict__ wg_, const float* __restrict__ bg_,
    const float* __restrict__ wi_, const float* __restrict__ bi_,
    const int* __restrict__ meta,
    unsigned short* __restrict__ hbuf)
{
  const int bid = blockIdx.x;
  const int e = bid >> 6;              // bid%8 = j%8 -> expert spread over XCDs
  const int j = bid & 63;              // 32-col stripe
  const int cnt = meta[e];
  const int poff = meta[3 * NEXP + e];
  const int padded = ((cnt + 127) >> 7) << 7;
  const int n0 = j * 32;

  // G slab 32K @0 | I slab 32K @32768
  __shared__ __align__(16) unsigned char lds[65536];

  const int t = threadIdx.x;
  const int l = t & 63, w = t >> 6;
  const int fr = l & 15, fg = l >> 4;

  // ---- one-time W conversion: f32 [k][n] -> slab [k>>3][n][k&7] (r12-proven) ----
  {
    const int r0 = t >> 1;             // 0..127
    const int h  = t & 1;              // 16-col half
    #pragma unroll
    for (int m = 0; m < 2; ++m) {
      const float* src = (m ? wi_ : wg_) + (size_t)e * DIM * HID + n0 + h * 16;
      unsigned char* slab = lds + m * 32768;
      #pragma unroll
      for (int p = 0; p < 4; ++p) {
        const int r = p * 128 + r0;    // k-row
        const float* row = src + (size_t)r * HID;
        float f[16];
        #pragma unroll
        for (int q = 0; q < 4; ++q) {
          float4 v = ((const float4*)row)[q];
          f[4*q] = v.x; f[4*q+1] = v.y; f[4*q+2] = v.z; f[4*q+3] = v.w;
        }
        unsigned char* dst = slab + ((r >> 3) * 32 + h * 16) * 16 + (r & 7) * 2;
        #pragma unroll
        for (int nn = 0; nn < 16; ++nn)
          *(unsigned short*)(dst + nn * 16) = f2bf(f[nn]);
      }
    }
  }
  __syncthreads();                     // slabs ready; read-only hereafter

  // biases for this wave's two 16-col fragments
  const float bg0 = bg_[(size_t)e * HID + n0 + fr];
  const float bg1 = bg_[(size_t)e * HID + n0 + 16 + fr];
  const float bi0 = bi_[(size_t)e * HID + n0 + fr];
  const float bi1 = bi_[(size_t)e * HID + n0 + 16 + fr];

  const int tile0 = poff >> 6;         // poff is 128-aligned

  for (int m0 = w * 32; m0 < padded; m0 += 128) {   // wave-owned 32-row tiles
    const unsigned short* abase = xp + (size_t)(tile0 + (m0 >> 6)) * 32768;
    const int rb = m0 & 32;            // row base within 64-row tile

    v4f aG00 = {0,0,0,0}, aG01 = {0,0,0,0}, aG10 = {0,0,0,0}, aG11 = {0,0,0,0};
    v4f aI00 = {0,0,0,0}, aI01 = {0,0,0,0}, aI10 = {0,0,0,0}, aI11 = {0,0,0,0};

    #pragma unroll 2
    for (int s = 0; s < 16; ++s) {     // K = 512, step 32; NO barrier
      const int kq = s * 4 + fg;       // 0..63
      v8s af0 = *(const v8s*)(abase + ((size_t)kq * 64 + rb + fr) * 8);
      v8s af1 = *(const v8s*)(abase + ((size_t)kq * 64 + rb + 16 + fr) * 8);
      v8s gf0 = *(const v8s*)(lds + ((kq * 32) + fr) * 16);
      v8s gf1 = *(const v8s*)(lds + ((kq * 32) + 16 + fr) * 16);
      v8s if0 = *(const v8s*)(lds + 32768 + ((kq * 32) + fr) * 16);
      v8s if1 = *(const v8s*)(lds + 32768 + ((kq * 32) + 16 + fr) * 16);
      aG00 = __builtin_amdgcn_mfma_f32_16x16x32_bf16(af0, gf0, aG00, 0, 0, 0);
      aG01 = __builtin_amdgcn_mfma_f32_16x16x32_bf16(af0, gf1, aG01, 0, 0, 0);
      aG10 = __builtin_amdgcn_mfma_f32_16x16x32_bf16(af1, gf0, aG10, 0, 0, 0);
      aG11 = __builtin_amdgcn_mfma_f32_16x16x32_bf16(af1, gf1, aG11, 0, 0, 0);
      aI00 = __builtin_amdgcn_mfma_f32_16x16x32_bf16(af0, if0, aI00, 0, 0, 0);
      aI01 = __builtin_amdgcn_mfma_f32_16x16x32_bf16(af0, if1, aI01, 0, 0, 0);
      aI10 = __builtin_amdgcn_mfma_f32_16x16x32_bf16(af1, if0, aI10, 0, 0, 0);
      aI11 = __builtin_amdgcn_mfma_f32_16x16x32_bf16(af1, if1, aI11, 0, 0, 0);
    }

    // epilogue: bias + SiLU(gate)*in -> hbuf panels (pad rows deterministic)
    #pragma unroll
    for (int nf = 0; nf < 2; ++nf) {
      const int c = n0 + nf * 16 + fr;
      const float bgv = nf ? bg1 : bg0;
      const float biv = nf ? bi1 : bi0;
      #pragma unroll
      for (int mf = 0; mf < 2; ++mf) {
        const v4f g4 = nf ? (mf ? aG11 : aG01) : (mf ? aG10 : aG00);
        const v4f i4 = nf ? (mf ? aI11 : aI01) : (mf ? aI10 : aI00);
        #pragma unroll
        for (int jj = 0; jj < 4; ++jj) {
          const int grow = poff + m0 + mf * 16 + fg * 4 + jj;
          const float g = g4[jj] + bgv;
          const float v = i4[jj] + biv;
          const float hval = g / (1.f + __expf(-g)) * v;
          hbuf[(size_t)(grow >> 6) * 131072 + ((size_t)(c >> 3) * 64 + (grow & 63)) * 8 + (c & 7)] = f2bf(hval);
        }
      }
    }
  }
}

// ---------------- GEMM2: out[perm] = h @ w_out + b_out (r10/r12-proven) ----------------
// BM=64, BN=64, BK=64, 256 thr, 4 waves 2x2, wave 32x32, both operands gload16.
__global__ __launch_bounds__(256, 4) void gemm2g(
    const unsigned short* __restrict__ hbuf,
    const unsigned short* __restrict__ wop, const float* __restrict__ bo_,
    const int* __restrict__ meta, const int* __restrict__ perm,
    float* __restrict__ out)
{
  const int bid = blockIdx.x;
  const int stripe = bid & 63;         // e*8 + jn
  const int mt = bid >> 6;
  const int e = stripe >> 3, jn = stripe & 7;
  const int cnt = meta[e];
  const int m0 = mt * 64;
  if (m0 >= cnt) return;
  const int off = meta[NEXP + e], poff = meta[3 * NEXP + e];
  const int n0 = jn * 64;

  // per buf (16384 B): A[8 kq][64 m][8] @0 (8K) | B[8 kq][64 n][8] @8192 (8K)
  __shared__ __align__(16) unsigned char lds[32768];

  const int t = threadIdx.x;
  const int l = t & 63, w = t >> 6;
  const int wm = w >> 1, wn = w & 1;
  const int fr = l & 15, fg = l >> 4;

  const unsigned short* pa = hbuf + (size_t)((poff + m0) >> 6) * 131072;
  const unsigned short* pb = wop + ((size_t)e * 8 + jn) * 131072;

  v4f acc[2][2];
  #pragma unroll
  for (int i = 0; i < 2; ++i) {
    acc[i][0] = (v4f){0.f, 0.f, 0.f, 0.f};
    acc[i][1] = (v4f){0.f, 0.f, 0.f, 0.f};
  }

  auto stage = [&](int s, int b) {
    unsigned char* base = lds + b * 16384;
    #pragma unroll
    for (int i = 0; i < 2; ++i) {
      const int c = t + 256 * i;
      gload16(pa + (size_t)s * 4096 + (size_t)c * 8, base + c * 16);
      gload16(pb + (size_t)s * 4096 + (size_t)c * 8, base + 8192 + c * 16);
    }
  };

  stage(0, 0);
  __syncthreads();

  int cur = 0;
  for (int s = 0; s < 32; ++s) {       // K = 2048 in 64-wide steps
    if (s < 31) stage(s + 1, cur ^ 1);
    const unsigned char* base = lds + cur * 16384;
    #pragma unroll
    for (int kk = 0; kk < 2; ++kk) {
      v8s af[2], bf[2];
      #pragma unroll
      for (int mf = 0; mf < 2; ++mf)
        af[mf] = *(const v8s*)(base + ((kk * 4 + fg) * 64 + wm * 32 + mf * 16 + fr) * 16);
      #pragma unroll
      for (int nf = 0; nf < 2; ++nf)
        bf[nf] = *(const v8s*)(base + 8192 + ((kk * 4 + fg) * 64 + wn * 32 + nf * 16 + fr) * 16);
      #pragma unroll
      for (int mf = 0; mf < 2; ++mf)
        #pragma unroll
        for (int nf = 0; nf < 2; ++nf)
          acc[mf][nf] = __builtin_amdgcn_mfma_f32_16x16x32_bf16(af[mf], bf[nf], acc[mf][nf], 0, 0, 0);
    }
    __syncthreads();
    cur ^= 1;
  }

  #pragma unroll
  for (int nf = 0; nf < 2; ++nf) {
    const int c = n0 + wn * 32 + nf * 16 + fr;
    const float bo = bo_[(size_t)e * DIM + c];
    #pragma unroll
    for (int mf = 0; mf < 2; ++mf)
      #pragma unroll
      for (int jj = 0; jj < 4; ++jj) {
        const int r = wm * 32 + mf * 16 + fg * 4 + jj;
        if (m0 + r < cnt)
          out[(size_t)perm[off + m0 + r] * DIM + c] = acc[mf][nf][jj] + bo;
      }
  }
}

// ---------------- launch ----------------
extern "C" void kernel_launch(void* const* d_in, const int* in_sizes, int n_in,
                              void* d_out, int out_size, void* d_ws, size_t ws_size,
                              hipStream_t stream) {
  const float* x      = (const float*)d_in[0];
  const int*   route  = (const int*)d_in[1];
  const float* w_in   = (const float*)d_in[2];
  const float* b_in   = (const float*)d_in[3];
  const float* w_gate = (const float*)d_in[4];
  const float* b_gate = (const float*)d_in[5];
  const float* w_out  = (const float*)d_in[6];
  const float* b_out  = (const float*)d_in[7];
  float* out = (float*)d_out;

  const int ntok = in_sizes[1];  // 4096

  int* meta = (int*)d_ws;
  int* perm = (int*)((char*)d_ws + 128);

  // ws: meta/perm 64K | xp 5.25MB | wop 16MB | hbuf 21MB  (~43 MB total)
  unsigned short* xp   = (unsigned short*)((char*)d_ws + 65536);
  unsigned short* wop  = (unsigned short*)((char*)d_ws + 65536 + 5242880);
  unsigned short* hbuf = (unsigned short*)((char*)d_ws + 65536 + 5242880 + 16777216);

  const int MT64 = (ntok + 63) / 64;

  route_prep<<<1, 256, 0, stream>>>(route, meta, ntok);
  fill_perm<<<(ntok + 255) / 256, 256, 0, stream>>>(route, meta, perm, ntok);
  x_conv<<<NEXP * MT64, 256, 0, stream>>>(x, meta, perm, xp);
  gemm1f2<<<NEXP * 64, 256, 0, stream>>>(
      xp, w_gate, b_gate, w_in, b_in, meta, hbuf);
  wo_conv<<<dim3(32, 8, 8), 256, 0, stream>>>(w_out, wop);
  gemm2g<<<64 * MT64, 256, 0, stream>>>(
      hbuf, wop, b_out, meta, perm, out);
}